// Round 2
// baseline (240.962 us; speedup 1.0000x reference)
//
#include <hip/hip_runtime.h>

constexpr int POOL = 7;
constexpr int NC = 256;     // channels
constexpr int CHUNK = 32;   // x positions staged in LDS per pass (32KB)

__global__ __launch_bounds__(256)
void roi_align_row_kernel(const float* __restrict__ boxes,
                          const int*   __restrict__ ishape,
                          const float* __restrict__ p2,
                          const float* __restrict__ p3,
                          const float* __restrict__ p4,
                          const float* __restrict__ p5,
                          float*       __restrict__ out,
                          int B, int N)
{
    __shared__ float vy[CHUNK][NC];   // y-combined taps: 32 x-positions x 256 ch

    int blk = blockIdx.x;             // (b, n, i)
    int i = blk % POOL;
    int n = (blk / POOL) % N;
    int b = blk / (POOL * N);
    int c = threadIdx.x;              // this thread's channel

    const float* bp = boxes + 4 * (b * N + n);
    float y1 = bp[0], x1 = bp[1], y2 = bp[2], x2 = bp[3];

    // ---- level selection (matches jnp: clip(4 + round(log2(sqrt(hw)/(224/sqrt(area)))), 2, 5)) ----
    float area  = (float)(ishape[0] * ishape[1]);
    float denom = 224.0f / sqrtf(area);
    float roi   = log2f(sqrtf((y2 - y1) * (x2 - x1)) / denom);
    int lvl = 4 + (int)rintf(roi);
    lvl = lvl < 2 ? 2 : (lvl > 5 ? 5 : lvl);

    const float* fm; int H;
    if      (lvl == 2) { fm = p2; H = 256; }
    else if (lvl == 3) { fm = p3; H = 128; }
    else if (lvl == 4) { fm = p4; H = 64;  }
    else               { fm = p5; H = 32;  }
    const int W = H;
    const float Hf = (float)H, Wf = (float)W;

    // ---- rounded, ordered box corners at this level ----
    float by1 = rintf(y1 * Hf), bx1 = rintf(x1 * Wf);
    float by2 = rintf(y2 * Hf), bx2 = rintf(x2 * Wf);
    float py1 = fminf(by1, by2), px1 = fminf(bx1, bx2);
    float py2 = fmaxf(by1, by2), px2 = fmaxf(bx1, bx2);

    // out index for (blk, j=0, c)
    size_t obase = (size_t)blk * POOL * NC + (size_t)c;

    if (py1 + px1 + py2 + px2 == 0.0f) {
        #pragma unroll
        for (int j = 0; j < POOL; ++j) out[obase + (size_t)j * NC] = 0.0f;
        return;
    }

    const float A = -0.5f;

    // ---- y-axis taps & cubic weights for this row i ----
    int iy[4]; float wy[4];
    {
        float span = py2 - py1;
        float grid = ((float)i + 0.5f) / (float)POOL;
        float s = py1 + grid * span - 0.5f;
        float f = floorf(s);
        float t = s - f;
        float hi_c = fmaxf(py2 - 1.0f, py1);
        float maxi = Hf - 1.0f;
        #pragma unroll
        for (int k = 0; k < 4; ++k) {
            float idx = f + (float)(k - 1);
            idx = fminf(fmaxf(idx, py1), hi_c);
            idx = fminf(fmaxf(idx, 0.0f), maxi);
            iy[k] = (int)idx;
        }
        float t2 = t * t, t3 = t2 * t;
        float u = 1.0f - t, u2 = u * u, u3 = u2 * u;
        wy[0] = A * (t3 - 2.0f * t2 + t);
        wy[1] = (A + 2.0f) * t3 - (A + 3.0f) * t2 + 1.0f;
        wy[2] = (A + 2.0f) * u3 - (A + 3.0f) * u2 + 1.0f;
        wy[3] = A * (t2 - t3);
    }

    // ---- x-axis taps & cubic weights for ALL 7 columns ----
    int   ix[POOL][4];
    float wx[POOL][4];
    {
        float span = px2 - px1;
        float hi_c = fmaxf(px2 - 1.0f, px1);
        float maxi = Wf - 1.0f;
        #pragma unroll
        for (int j = 0; j < POOL; ++j) {
            float grid = ((float)j + 0.5f) / (float)POOL;
            float s = px1 + grid * span - 0.5f;
            float f = floorf(s);
            float t = s - f;
            #pragma unroll
            for (int l = 0; l < 4; ++l) {
                float idx = f + (float)(l - 1);
                idx = fminf(fmaxf(idx, px1), hi_c);
                idx = fminf(fmaxf(idx, 0.0f), maxi);
                ix[j][l] = (int)idx;
            }
            float t2 = t * t, t3 = t2 * t;
            float u = 1.0f - t, u2 = u * u, u3 = u2 * u;
            wx[j][0] = A * (t3 - 2.0f * t2 + t);
            wx[j][1] = (A + 2.0f) * t3 - (A + 3.0f) * t2 + 1.0f;
            wx[j][2] = (A + 2.0f) * u3 - (A + 3.0f) * u2 + 1.0f;
            wx[j][3] = A * (t2 - t3);
        }
    }

    // taps are monotone non-decreasing over (j,l): union is [x_lo, x_hi]
    int x_lo = ix[0][0];
    int x_hi = ix[POOL - 1][3];

    // per-row base pointers (this thread's channel)
    const float* row0 = fm + ((size_t)b * H + iy[0]) * (size_t)(W * NC) + c;
    const float* row1 = fm + ((size_t)b * H + iy[1]) * (size_t)(W * NC) + c;
    const float* row2 = fm + ((size_t)b * H + iy[2]) * (size_t)(W * NC) + c;
    const float* row3 = fm + ((size_t)b * H + iy[3]) * (size_t)(W * NC) + c;

    float acc[POOL];
    #pragma unroll
    for (int j = 0; j < POOL; ++j) acc[j] = 0.0f;

    for (int x0 = x_lo; x0 <= x_hi; x0 += CHUNK) {
        int xe = x0 + CHUNK - 1;
        if (xe > x_hi) xe = x_hi;

        if (x0 > x_lo) __syncthreads();   // protect LDS reuse across chunks

        // phase 1: y-combine the needed x positions into LDS
        for (int x = x0; x <= xe; ++x) {
            size_t o = (size_t)x * NC;
            float v = wy[0] * row0[o] + wy[1] * row1[o]
                    + wy[2] * row2[o] + wy[3] * row3[o];
            vy[x - x0][c] = v;
        }
        __syncthreads();

        // phase 2: x-taps from LDS
        #pragma unroll
        for (int j = 0; j < POOL; ++j) {
            #pragma unroll
            for (int l = 0; l < 4; ++l) {
                int xr = ix[j][l] - x0;
                if (xr >= 0 && xr <= xe - x0)
                    acc[j] += wx[j][l] * vy[xr][c];
            }
        }
    }

    #pragma unroll
    for (int j = 0; j < POOL; ++j)
        out[obase + (size_t)j * NC] = acc[j];
}

extern "C" void kernel_launch(void* const* d_in, const int* in_sizes, int n_in,
                              void* d_out, int out_size, void* d_ws, size_t ws_size,
                              hipStream_t stream) {
    const float* boxes  = (const float*)d_in[0];
    const int*   ishape = (const int*)d_in[1];
    const float* p2     = (const float*)d_in[2];
    const float* p3     = (const float*)d_in[3];
    const float* p4     = (const float*)d_in[4];
    const float* p5     = (const float*)d_in[5];
    float* out = (float*)d_out;

    int B = in_sizes[2] / (256 * 256 * 256);   // p2 = B x 256 x 256 x 256
    int N = in_sizes[0] / (4 * B);             // boxes = B x N x 4

    int blocks = B * N * POOL;                 // one block per output row (b,n,i)
    roi_align_row_kernel<<<blocks, 256, 0, stream>>>(boxes, ishape, p2, p3, p4, p5, out, B, N);
}

// Round 3
// 233.331 us; speedup vs baseline: 1.0327x; 1.0327x over previous
//
#include <hip/hip_runtime.h>

constexpr int POOL = 7;
constexpr int NC = 256;   // channels

// One 64-lane wave per output row (b, n, i). Lane owns 4 channels (float4).
// Stream the union x-range once: y-combine 4 row taps per x, then accumulate
// into the 7 j-cells with wave-uniform tap-match weights.
__global__ __launch_bounds__(256)
void roi_align_wave_row(const float* __restrict__ boxes,
                        const int*   __restrict__ ishape,
                        const float* __restrict__ p2,
                        const float* __restrict__ p3,
                        const float* __restrict__ p4,
                        const float* __restrict__ p5,
                        float*       __restrict__ out,
                        int N, int nrows)
{
    int row  = (blockIdx.x << 2) + (threadIdx.x >> 6);   // (b, n, i)
    if (row >= nrows) return;
    int lane = threadIdx.x & 63;

    int i  = row % POOL;
    int bn = row / POOL;
    int n  = bn % N;
    int b  = bn / N;

    const float* bp = boxes + 4 * (b * N + n);
    float y1 = bp[0], x1 = bp[1], y2 = bp[2], x2 = bp[3];

    // ---- level selection: clip(4 + round(log2(sqrt(hw)/(224/sqrt(area)))), 2, 5) ----
    float area  = (float)(ishape[0] * ishape[1]);
    float denom = 224.0f / sqrtf(area);
    float roi   = log2f(sqrtf((y2 - y1) * (x2 - x1)) / denom);
    int lvl = 4 + (int)rintf(roi);
    lvl = lvl < 2 ? 2 : (lvl > 5 ? 5 : lvl);

    const float* fm; int H;
    if      (lvl == 2) { fm = p2; H = 256; }
    else if (lvl == 3) { fm = p3; H = 128; }
    else if (lvl == 4) { fm = p4; H = 64;  }
    else               { fm = p5; H = 32;  }
    const int W = H;
    const float Hf = (float)H, Wf = (float)W;

    // ---- rounded, ordered box corners at this level ----
    float by1 = rintf(y1 * Hf), bx1 = rintf(x1 * Wf);
    float by2 = rintf(y2 * Hf), bx2 = rintf(x2 * Wf);
    float py1 = fminf(by1, by2), px1 = fminf(bx1, bx2);
    float py2 = fmaxf(by1, by2), px2 = fmaxf(bx1, bx2);

    float* obase = out + (size_t)row * (POOL * NC) + (size_t)lane * 4;

    if (py1 + px1 + py2 + px2 == 0.0f) {
        float4 z = {0.f, 0.f, 0.f, 0.f};
        #pragma unroll
        for (int j = 0; j < POOL; ++j)
            *(float4*)(obase + (size_t)j * NC) = z;
        return;
    }

    const float A = -0.5f;

    // ---- y taps & weights for this row i ----
    int iy[4]; float wy[4];
    {
        float span = py2 - py1;
        float grid = ((float)i + 0.5f) / (float)POOL;
        float s = py1 + grid * span - 0.5f;
        float f = floorf(s);
        float t = s - f;
        float hi_c = fmaxf(py2 - 1.0f, py1);
        float maxi = Hf - 1.0f;
        #pragma unroll
        for (int k = 0; k < 4; ++k) {
            float idx = f + (float)(k - 1);
            idx = fminf(fmaxf(idx, py1), hi_c);
            idx = fminf(fmaxf(idx, 0.0f), maxi);
            iy[k] = (int)idx;
        }
        float t2 = t * t, t3 = t2 * t;
        float u = 1.0f - t, u2 = u * u, u3 = u2 * u;
        wy[0] = A * (t3 - 2.0f * t2 + t);
        wy[1] = (A + 2.0f) * t3 - (A + 3.0f) * t2 + 1.0f;
        wy[2] = (A + 2.0f) * u3 - (A + 3.0f) * u2 + 1.0f;
        wy[3] = A * (t2 - t3);
    }

    // ---- x taps & weights for all 7 columns (wave-uniform) ----
    int   ix[POOL][4];
    float wx[POOL][4];
    {
        float span = px2 - px1;
        float hi_c = fmaxf(px2 - 1.0f, px1);
        float maxi = Wf - 1.0f;
        #pragma unroll
        for (int j = 0; j < POOL; ++j) {
            float grid = ((float)j + 0.5f) / (float)POOL;
            float s = px1 + grid * span - 0.5f;
            float f = floorf(s);
            float t = s - f;
            #pragma unroll
            for (int l = 0; l < 4; ++l) {
                float idx = f + (float)(l - 1);
                idx = fminf(fmaxf(idx, px1), hi_c);
                idx = fminf(fmaxf(idx, 0.0f), maxi);
                ix[j][l] = (int)idx;
            }
            float t2 = t * t, t3 = t2 * t;
            float u = 1.0f - t, u2 = u * u, u3 = u2 * u;
            wx[j][0] = A * (t3 - 2.0f * t2 + t);
            wx[j][1] = (A + 2.0f) * t3 - (A + 3.0f) * t2 + 1.0f;
            wx[j][2] = (A + 2.0f) * u3 - (A + 3.0f) * u2 + 1.0f;
            wx[j][3] = A * (t2 - t3);
        }
    }

    // taps are monotone non-decreasing: union x-range is contiguous
    int x_lo = ix[0][0];
    int x_hi = ix[POOL - 1][3];

    const size_t rstride = (size_t)(W * NC);
    const float* r0 = fm + ((size_t)b * H + iy[0]) * rstride + (size_t)lane * 4;
    const float* r1 = fm + ((size_t)b * H + iy[1]) * rstride + (size_t)lane * 4;
    const float* r2 = fm + ((size_t)b * H + iy[2]) * rstride + (size_t)lane * 4;
    const float* r3 = fm + ((size_t)b * H + iy[3]) * rstride + (size_t)lane * 4;

    float4 acc[POOL];
    #pragma unroll
    for (int j = 0; j < POOL; ++j) acc[j] = make_float4(0.f, 0.f, 0.f, 0.f);

    // 2-stage pipeline over the x stream
    size_t o = (size_t)x_lo * NC;
    float4 n0 = *(const float4*)(r0 + o);
    float4 n1 = *(const float4*)(r1 + o);
    float4 n2 = *(const float4*)(r2 + o);
    float4 n3 = *(const float4*)(r3 + o);

    for (int x = x_lo; x <= x_hi; ++x) {
        float4 c0 = n0, c1 = n1, c2 = n2, c3 = n3;
        if (x < x_hi) {
            size_t on = (size_t)(x + 1) * NC;
            n0 = *(const float4*)(r0 + on);
            n1 = *(const float4*)(r1 + on);
            n2 = *(const float4*)(r2 + on);
            n3 = *(const float4*)(r3 + on);
        }
        // y-combine
        float4 v;
        v.x = wy[0] * c0.x + wy[1] * c1.x + wy[2] * c2.x + wy[3] * c3.x;
        v.y = wy[0] * c0.y + wy[1] * c1.y + wy[2] * c2.y + wy[3] * c3.y;
        v.z = wy[0] * c0.z + wy[1] * c1.z + wy[2] * c2.z + wy[3] * c3.z;
        v.w = wy[0] * c0.w + wy[1] * c1.w + wy[2] * c2.w + wy[3] * c3.w;

        // accumulate into matching cells (all wave-uniform scalar weights)
        #pragma unroll
        for (int j = 0; j < POOL; ++j) {
            float w = 0.f;
            #pragma unroll
            for (int l = 0; l < 4; ++l)
                if (x == ix[j][l]) w += wx[j][l];
            if (w != 0.f) {
                acc[j].x += w * v.x;
                acc[j].y += w * v.y;
                acc[j].z += w * v.z;
                acc[j].w += w * v.w;
            }
        }
    }

    #pragma unroll
    for (int j = 0; j < POOL; ++j)
        *(float4*)(obase + (size_t)j * NC) = acc[j];
}

extern "C" void kernel_launch(void* const* d_in, const int* in_sizes, int n_in,
                              void* d_out, int out_size, void* d_ws, size_t ws_size,
                              hipStream_t stream) {
    const float* boxes  = (const float*)d_in[0];
    const int*   ishape = (const int*)d_in[1];
    const float* p2     = (const float*)d_in[2];
    const float* p3     = (const float*)d_in[3];
    const float* p4     = (const float*)d_in[4];
    const float* p5     = (const float*)d_in[5];
    float* out = (float*)d_out;

    int B = in_sizes[2] / (256 * 256 * 256);   // p2 = B x 256 x 256 x 256
    int N = in_sizes[0] / (4 * B);             // boxes = B x N x 4

    int nrows  = B * N * POOL;                 // one wave per output row
    int blocks = (nrows + 3) / 4;              // 4 waves (256 threads) per block
    roi_align_wave_row<<<blocks, 256, 0, stream>>>(boxes, ishape, p2, p3, p4, p5,
                                                   out, N, nrows);
}

// Round 5
// 210.498 us; speedup vs baseline: 1.1447x; 1.1085x over previous
//
#include <hip/hip_runtime.h>

constexpr int POOL = 7;
constexpr int NC = 256;   // channels
constexpr int NXCD = 8;

// One 64-lane wave per output cell (b,n,i,j); lane owns 4 channels (float4).
// 16 independent 1KB tap loads per wave. XCD-chunked block swizzle keeps all
// cells of an ROI on one XCD so tap re-reads hit that XCD's L2.
__global__ __launch_bounds__(256)
void roi_align_cell_swz(const float* __restrict__ boxes,
                        const int*   __restrict__ ishape,
                        const float* __restrict__ p2,
                        const float* __restrict__ p3,
                        const float* __restrict__ p4,
                        const float* __restrict__ p5,
                        float*       __restrict__ out,
                        int N, int ncells, int nwg)
{
    // bijective XCD-chunked swizzle (m204): XCD (bid%8) owns a contiguous chunk
    int bid = blockIdx.x;
    int q = nwg / NXCD, r = nwg % NXCD;
    int xcd = bid % NXCD, idx = bid / NXCD;
    int wgid = (xcd < r ? xcd * (q + 1) : r * (q + 1) + (xcd - r) * q) + idx;

    int cell = (wgid << 2) + (threadIdx.x >> 6);
    if (cell >= ncells) return;
    int lane = threadIdx.x & 63;

    int j = cell % POOL;
    int i = (cell / POOL) % POOL;
    int n = (cell / (POOL * POOL)) % N;
    int b = cell / (POOL * POOL * N);

    const float* bp = boxes + 4 * (b * N + n);
    float y1 = bp[0], x1 = bp[1], y2 = bp[2], x2 = bp[3];

    // ---- level selection: clip(4 + round(log2(sqrt(hw)/(224/sqrt(area)))), 2, 5) ----
    float area  = (float)(ishape[0] * ishape[1]);
    float denom = 224.0f / sqrtf(area);
    float roi   = log2f(sqrtf((y2 - y1) * (x2 - x1)) / denom);
    int lvl = 4 + (int)rintf(roi);
    lvl = lvl < 2 ? 2 : (lvl > 5 ? 5 : lvl);

    const float* fm; int H;
    if      (lvl == 2) { fm = p2; H = 256; }
    else if (lvl == 3) { fm = p3; H = 128; }
    else if (lvl == 4) { fm = p4; H = 64;  }
    else               { fm = p5; H = 32;  }
    const int W = H;
    const float Hf = (float)H, Wf = (float)W;

    // ---- rounded, ordered box corners at this level ----
    float by1 = rintf(y1 * Hf), bx1 = rintf(x1 * Wf);
    float by2 = rintf(y2 * Hf), bx2 = rintf(x2 * Wf);
    float py1 = fminf(by1, by2), px1 = fminf(bx1, bx2);
    float py2 = fmaxf(by1, by2), px2 = fmaxf(bx1, bx2);

    float* op = out + (size_t)cell * NC + (size_t)lane * 4;

    if (py1 + px1 + py2 + px2 == 0.0f) {
        float4 z = {0.f, 0.f, 0.f, 0.f};
        *(float4*)op = z;
        return;
    }

    const float A = -0.5f;

    // ---- y taps & weights for this i ----
    int iy[4]; float wy[4];
    {
        float span = py2 - py1;
        float grid = ((float)i + 0.5f) / (float)POOL;
        float s = py1 + grid * span - 0.5f;
        float f = floorf(s);
        float t = s - f;
        float hi_c = fmaxf(py2 - 1.0f, py1);
        float maxi = Hf - 1.0f;
        #pragma unroll
        for (int k = 0; k < 4; ++k) {
            float v = f + (float)(k - 1);
            v = fminf(fmaxf(v, py1), hi_c);
            v = fminf(fmaxf(v, 0.0f), maxi);
            iy[k] = (int)v;
        }
        float t2 = t * t, t3 = t2 * t;
        float u = 1.0f - t, u2 = u * u, u3 = u2 * u;
        wy[0] = A * (t3 - 2.0f * t2 + t);
        wy[1] = (A + 2.0f) * t3 - (A + 3.0f) * t2 + 1.0f;
        wy[2] = (A + 2.0f) * u3 - (A + 3.0f) * u2 + 1.0f;
        wy[3] = A * (t2 - t3);
    }

    // ---- x taps & weights for this j ----
    int ix[4]; float wx[4];
    {
        float span = px2 - px1;
        float grid = ((float)j + 0.5f) / (float)POOL;
        float s = px1 + grid * span - 0.5f;
        float f = floorf(s);
        float t = s - f;
        float hi_c = fmaxf(px2 - 1.0f, px1);
        float maxi = Wf - 1.0f;
        #pragma unroll
        for (int l = 0; l < 4; ++l) {
            float v = f + (float)(l - 1);
            v = fminf(fmaxf(v, px1), hi_c);
            v = fminf(fmaxf(v, 0.0f), maxi);
            ix[l] = (int)v;
        }
        float t2 = t * t, t3 = t2 * t;
        float u = 1.0f - t, u2 = u * u, u3 = u2 * u;
        wx[0] = A * (t3 - 2.0f * t2 + t);
        wx[1] = (A + 2.0f) * t3 - (A + 3.0f) * t2 + 1.0f;
        wx[2] = (A + 2.0f) * u3 - (A + 3.0f) * u2 + 1.0f;
        wx[3] = A * (t2 - t3);
    }

    // ---- 16 independent coalesced tap loads, weighted accumulate ----
    float4 acc = {0.f, 0.f, 0.f, 0.f};
    const size_t bbase = (size_t)b * H * W * NC + (size_t)lane * 4;
    #pragma unroll
    for (int k = 0; k < 4; ++k) {
        const float* row = fm + bbase + (size_t)iy[k] * (size_t)(W * NC);
        #pragma unroll
        for (int l = 0; l < 4; ++l) {
            float wgt = wy[k] * wx[l];
            float4 v = *(const float4*)(row + (size_t)ix[l] * NC);
            acc.x += wgt * v.x;
            acc.y += wgt * v.y;
            acc.z += wgt * v.z;
            acc.w += wgt * v.w;
        }
    }
    *(float4*)op = acc;
}

extern "C" void kernel_launch(void* const* d_in, const int* in_sizes, int n_in,
                              void* d_out, int out_size, void* d_ws, size_t ws_size,
                              hipStream_t stream) {
    const float* boxes  = (const float*)d_in[0];
    const int*   ishape = (const int*)d_in[1];
    const float* p2     = (const float*)d_in[2];
    const float* p3     = (const float*)d_in[3];
    const float* p4     = (const float*)d_in[4];
    const float* p5     = (const float*)d_in[5];
    float* out = (float*)d_out;

    int B = in_sizes[2] / (256 * 256 * 256);   // p2 = B x 256 x 256 x 256
    int N = in_sizes[0] / (4 * B);             // boxes = B x N x 4

    int ncells = B * N * POOL * POOL;
    int nwg = (ncells + 3) / 4;                // 4 cells (waves) per block
    roi_align_cell_swz<<<nwg, 256, 0, stream>>>(boxes, ishape, p2, p3, p4, p5,
                                                out, N, ncells, nwg);
}